// Round 2
// baseline (1629.129 us; speedup 1.0000x reference)
//
#include <hip/hip_runtime.h>
#include <stdint.h>

// Problem constants: B=4, L=4096, D=2048, I=5632
#define D_DIM 2048
#define I_DIM 5632
#define NTOK  16384          // B*L
#define MROWS 16512          // 129 * 128 (worst case: align128(n0) + n1)
#define MTILES 129
#define CH0   65             // M-tiles in chunk 0
#define CH1   64             // M-tiles in chunk 1
#define HROWS (CH0 * 128)    // h-buffer rows (max chunk)

using f32x4  = __attribute__((ext_vector_type(4))) float;
using bf16x8 = __attribute__((ext_vector_type(8))) __bf16;
using u16x8  = __attribute__((ext_vector_type(8))) unsigned short;
using u16x4  = __attribute__((ext_vector_type(4))) unsigned short;
typedef unsigned short ushort;

__device__ __forceinline__ ushort f2bf(float f) {
  union { float f; unsigned int u; } v; v.f = f;
  unsigned int r = v.u + 0x7fffu + ((v.u >> 16) & 1u);   // RNE
  return (ushort)(r >> 16);
}

__device__ __forceinline__ void glds16(const void* g, void* l) {
  __builtin_amdgcn_global_load_lds(
      (__attribute__((address_space(1))) void*)(g),
      (__attribute__((address_space(3))) void*)(l),
      16, 0, 0);
}

// ---------------- mask scan ----------------
__global__ void count_kernel(const int* __restrict__ mask, int* __restrict__ cnt) {
  int i = blockIdx.x * 256 + threadIdx.x;
  if (i < NTOK && mask[i] == 0) atomicAdd(&cnt[0], 1);
}

__global__ void assign_kernel(const int* __restrict__ mask, int* __restrict__ cnt,
                              int* __restrict__ rowmap) {
  int i = blockIdx.x * 256 + threadIdx.x;
  if (i >= NTOK) return;
  int n0  = cnt[0];                 // count of und (mask==0) tokens
  int n0p = (n0 + 127) & ~127;
  int row;
  if (mask[i] == 0) row = atomicAdd(&cnt[1], 1);
  else              row = n0p + atomicAdd(&cnt[2], 1);
  rowmap[row] = i;
}

// ---------------- fp32 -> bf16 flat cast (x) ----------------
__global__ __launch_bounds__(256) void cast_x_kernel(const float* __restrict__ in,
                                                     ushort* __restrict__ out) {
  int i = blockIdx.x * 256 + threadIdx.x;     // float4 index; grid covers exactly
  f32x4 v = ((const f32x4*)in)[i];
  u16x4 o;
#pragma unroll
  for (int j = 0; j < 4; j++) o[j] = f2bf(v[j]);
  ((u16x4*)out)[i] = o;
}

// ---------------- weight transpose+cast: fp32 (R,C) -> bf16 (C,R) ----------------
__global__ __launch_bounds__(256) void transpose_cast_kernel(
    const float* __restrict__ in, ushort* __restrict__ out, int R, int C) {
  __shared__ ushort s[64][72];      // +8 pad breaks bank conflicts, keeps 16B rows
  int tC = blockIdx.x, tR = blockIdx.y;
  int tid = threadIdx.x;
  // load phase: 64x64 fp32 tile, each thread 4 floats x 4 rows
  int r0 = tid >> 4;                // 0..15
  int c4 = (tid & 15) * 4;          // 0..60
  const float* src = in + (size_t)(tR * 64 + r0) * C + tC * 64 + c4;
#pragma unroll
  for (int rr = 0; rr < 64; rr += 16) {
    f32x4 v = *(const f32x4*)(src + (size_t)rr * C);
#pragma unroll
    for (int j = 0; j < 4; j++) s[r0 + rr][c4 + j] = f2bf(v[j]);
  }
  __syncthreads();
  // store phase: bf16 rows of the transposed tile
  int r8 = tid >> 3;                // 0..31
  int c8 = (tid & 7) * 8;           // 0..56
#pragma unroll
  for (int rr = 0; rr < 64; rr += 32) {
    int orow = r8 + rr;
    u16x8 v;
#pragma unroll
    for (int j = 0; j < 8; j++) v[j] = s[c8 + j][orow];
    *(u16x8*)(out + (size_t)(tC * 64 + orow) * R + tR * 64 + c8) = v;
  }
}

// ---------------- fused gate+up GEMM + swiglu ----------------
// A: gathered bf16 x rows (via rowmap), (M, K=2048)
// B: transposed bf16 weights (I, D); wt = [und_gate_t, und_up_t, gen_gate_t, gen_up_t]
// out: h (chunk-local rows, 5632) bf16
__global__ __launch_bounds__(256, 2)
void gateup_kernel(const ushort* __restrict__ x, const int* __restrict__ rowmap,
                   const int* __restrict__ cnt, const ushort* __restrict__ wt,
                   ushort* __restrict__ h, int mbase) {
  __shared__ ushort sA[128 * 64];
  __shared__ ushort sG[128 * 64];
  __shared__ ushort sU[128 * 64];

  const int bn = blockIdx.x, bm = blockIdx.y;
  const int gtile = mbase + bm;               // global M-tile
  const int tid = threadIdx.x;
  const int lane = tid & 63, wave = tid >> 6;
  const int wm = (wave & 1) * 64, wn = (wave >> 1) * 64;
  const int lrow = lane & 15, quad = lane >> 4;

  const int n0p = (cnt[0] + 127) & ~127;
  const int grp = (gtile * 128 >= n0p) ? 1 : 0;
  const size_t WSZ = (size_t)I_DIM * D_DIM;
  const ushort* Wg = wt + (size_t)(grp * 2) * WSZ;
  const ushort* Wu = Wg + WSZ;

  // staging: g = is*256+tid -> row r = g>>3, lds chunk c = g&7,
  // global chunk cs = c ^ (r&7)  (XOR swizzle -> conflict-free frag reads)
  const ushort *aP[4], *gP[4], *uP[4];
#pragma unroll
  for (int is = 0; is < 4; is++) {
    int g = is * 256 + tid;
    int r = g >> 3, c = g & 7;
    int cs = c ^ (r & 7);
    int tok = rowmap[gtile * 128 + r];
    if (tok < 0) tok = 0;           // gap rows: harmless garbage, never scattered
    aP[is] = x  + (size_t)tok * D_DIM + cs * 8;
    gP[is] = Wg + (size_t)(bn * 128 + r) * D_DIM + cs * 8;
    uP[is] = Wu + (size_t)(bn * 128 + r) * D_DIM + cs * 8;
  }

  f32x4 accG[4][4], accU[4][4];
#pragma unroll
  for (int i = 0; i < 4; i++)
#pragma unroll
    for (int j = 0; j < 4; j++) {
      accG[i][j] = (f32x4){0.f, 0.f, 0.f, 0.f};
      accU[i][j] = (f32x4){0.f, 0.f, 0.f, 0.f};
    }

  for (int k0 = 0; k0 < D_DIM; k0 += 64) {
#pragma unroll
    for (int is = 0; is < 4; is++) {
      // wave-uniform LDS base; HW places lane l at base + l*16B
      int wbase = (is * 256 + wave * 64) * 8;
      glds16(aP[is] + k0, &sA[wbase]);
      glds16(gP[is] + k0, &sG[wbase]);
      glds16(uP[is] + k0, &sU[wbase]);
    }
    __syncthreads();
#pragma unroll
    for (int kk = 0; kk < 2; kk++) {
      const int co = ((kk * 4 + quad) ^ (lane & 7)) * 8;
      bf16x8 af[4], gf[4], uf[4];
#pragma unroll
      for (int i = 0; i < 4; i++) af[i] = *(const bf16x8*)&sA[(wm + i * 16 + lrow) * 64 + co];
#pragma unroll
      for (int j = 0; j < 4; j++) gf[j] = *(const bf16x8*)&sG[(wn + j * 16 + lrow) * 64 + co];
#pragma unroll
      for (int j = 0; j < 4; j++) uf[j] = *(const bf16x8*)&sU[(wn + j * 16 + lrow) * 64 + co];
#pragma unroll
      for (int i = 0; i < 4; i++)
#pragma unroll
        for (int j = 0; j < 4; j++) {
          accG[i][j] = __builtin_amdgcn_mfma_f32_16x16x32_bf16(af[i], gf[j], accG[i][j], 0, 0, 0);
          accU[i][j] = __builtin_amdgcn_mfma_f32_16x16x32_bf16(af[i], uf[j], accU[i][j], 0, 0, 0);
        }
    }
    __syncthreads();
  }

  // epilogue: h = silu(g) * u, bf16, chunk-local rows
#pragma unroll
  for (int i = 0; i < 4; i++) {
    int rbase = bm * 128 + wm + i * 16 + quad * 4;
#pragma unroll
    for (int j = 0; j < 4; j++) {
      int col = bn * 128 + wn + j * 16 + lrow;
#pragma unroll
      for (int r = 0; r < 4; r++) {
        float g = accG[i][j][r];
        float u = accU[i][j][r];
        float s = g / (1.f + __expf(-g));
        h[(size_t)(rbase + r) * I_DIM + col] = f2bf(s * u);
      }
    }
  }
}

// ---------------- down GEMM + scatter (fp32 out) ----------------
__global__ __launch_bounds__(256, 2)
void down_kernel(const ushort* __restrict__ h, const int* __restrict__ rowmap,
                 const int* __restrict__ cnt, const ushort* __restrict__ wdt,
                 float* __restrict__ out, int mbase) {
  __shared__ ushort sA[128 * 64];
  __shared__ ushort sB[128 * 64];

  const int bn = blockIdx.x, bm = blockIdx.y;
  const int gtile = mbase + bm;
  const int tid = threadIdx.x;
  const int lane = tid & 63, wave = tid >> 6;
  const int wm = (wave & 1) * 64, wn = (wave >> 1) * 64;
  const int lrow = lane & 15, quad = lane >> 4;

  const int n0p = (cnt[0] + 127) & ~127;
  const int grp = (gtile * 128 >= n0p) ? 1 : 0;
  const ushort* W = wdt + (size_t)grp * ((size_t)D_DIM * I_DIM);

  const ushort *aP[4], *bP[4];
#pragma unroll
  for (int is = 0; is < 4; is++) {
    int g = is * 256 + tid;
    int r = g >> 3, c = g & 7;
    int cs = c ^ (r & 7);
    aP[is] = h + (size_t)(bm * 128 + r) * I_DIM + cs * 8;     // chunk-local
    bP[is] = W + (size_t)(bn * 128 + r) * I_DIM + cs * 8;
  }

  f32x4 acc[4][4];
#pragma unroll
  for (int i = 0; i < 4; i++)
#pragma unroll
    for (int j = 0; j < 4; j++) acc[i][j] = (f32x4){0.f, 0.f, 0.f, 0.f};

  for (int k0 = 0; k0 < I_DIM; k0 += 64) {
#pragma unroll
    for (int is = 0; is < 4; is++) {
      int wbase = (is * 256 + wave * 64) * 8;
      glds16(aP[is] + k0, &sA[wbase]);
      glds16(bP[is] + k0, &sB[wbase]);
    }
    __syncthreads();
#pragma unroll
    for (int kk = 0; kk < 2; kk++) {
      const int co = ((kk * 4 + quad) ^ (lane & 7)) * 8;
      bf16x8 af[4], bf[4];
#pragma unroll
      for (int i = 0; i < 4; i++) af[i] = *(const bf16x8*)&sA[(wm + i * 16 + lrow) * 64 + co];
#pragma unroll
      for (int j = 0; j < 4; j++) bf[j] = *(const bf16x8*)&sB[(wn + j * 16 + lrow) * 64 + co];
#pragma unroll
      for (int i = 0; i < 4; i++)
#pragma unroll
        for (int j = 0; j < 4; j++)
          acc[i][j] = __builtin_amdgcn_mfma_f32_16x16x32_bf16(af[i], bf[j], acc[i][j], 0, 0, 0);
    }
    __syncthreads();
  }

  // epilogue: scatter fp32 rows to out[token]
#pragma unroll
  for (int i = 0; i < 4; i++) {
    int rbase = gtile * 128 + wm + i * 16 + quad * 4;
#pragma unroll
    for (int r = 0; r < 4; r++) {
      int tok = rowmap[rbase + r];
      if (tok < 0) continue;
#pragma unroll
      for (int j = 0; j < 4; j++) {
        int col = bn * 128 + wn + j * 16 + lrow;
        out[(size_t)tok * D_DIM + col] = acc[i][j][r];
      }
    }
  }
}

extern "C" void kernel_launch(void* const* d_in, const int* in_sizes, int n_in,
                              void* d_out, int out_size, void* d_ws, size_t ws_size,
                              hipStream_t stream) {
  const float* x   = (const float*)d_in[0];    // hidden_states fp32 (16384, 2048)
  const int* mask  = (const int*)d_in[1];      // gen_token_mask int32 (16384)
  const float* ug  = (const float*)d_in[2];    // und_gate fp32 (D,I)
  const float* uu  = (const float*)d_in[3];    // und_up   (D,I)
  const float* ud  = (const float*)d_in[4];    // und_down (I,D)
  const float* gg  = (const float*)d_in[5];    // gen_gate (D,I)
  const float* gu  = (const float*)d_in[6];    // gen_up   (D,I)
  const float* gd  = (const float*)d_in[7];    // gen_down (I,D)
  float* out = (float*)d_out;

  // ws layout (~285.4 MB):
  //   [0,256)    counters   | [256,+66048) rowmap[16512]
  //   xb:  bf16 x (16384,2048)           67,108,864 B
  //   wt:  6 transposed bf16 weights    138,412,032 B
  //   h:   bf16 (8320, 5632)             93,716,480 B
  char* ws = (char*)d_ws;
  int* cnt    = (int*)ws;
  int* rowmap = (int*)(ws + 256);
  ushort* xb  = (ushort*)(ws + 256 + 66048);
  ushort* wt  = xb + (size_t)NTOK * D_DIM;
  const size_t WSZ = (size_t)I_DIM * D_DIM;     // 11534336
  ushort* hbuf = wt + 6 * WSZ;

  hipMemsetAsync(cnt, 0, 256, stream);
  hipMemsetAsync(rowmap, 0xFF, MROWS * sizeof(int), stream);   // -1
  count_kernel<<<64, 256, 0, stream>>>(mask, cnt);
  assign_kernel<<<64, 256, 0, stream>>>(mask, cnt, rowmap);

  cast_x_kernel<<<(NTOK * D_DIM / 4) / 256, 256, 0, stream>>>(x, xb);

  // gate/up: (D=2048, I=5632) -> (I, D); down: (I=5632, D=2048) -> (D, I)
  transpose_cast_kernel<<<dim3(88, 32), 256, 0, stream>>>(ug, wt + 0 * WSZ, 2048, 5632);
  transpose_cast_kernel<<<dim3(88, 32), 256, 0, stream>>>(uu, wt + 1 * WSZ, 2048, 5632);
  transpose_cast_kernel<<<dim3(88, 32), 256, 0, stream>>>(gg, wt + 2 * WSZ, 2048, 5632);
  transpose_cast_kernel<<<dim3(88, 32), 256, 0, stream>>>(gu, wt + 3 * WSZ, 2048, 5632);
  transpose_cast_kernel<<<dim3(32, 88), 256, 0, stream>>>(ud, wt + 4 * WSZ, 5632, 2048);
  transpose_cast_kernel<<<dim3(32, 88), 256, 0, stream>>>(gd, wt + 5 * WSZ, 5632, 2048);

  // chunked M to bound the h buffer: tiles [0,65) then [65,129)
  gateup_kernel<<<dim3(I_DIM / 128, CH0), 256, 0, stream>>>(xb, rowmap, cnt, wt, hbuf, 0);
  down_kernel<<<dim3(D_DIM / 128, CH0), 256, 0, stream>>>(hbuf, rowmap, cnt, wt + 4 * WSZ, out, 0);
  gateup_kernel<<<dim3(I_DIM / 128, CH1), 256, 0, stream>>>(xb, rowmap, cnt, wt, hbuf, CH0);
  down_kernel<<<dim3(D_DIM / 128, CH1), 256, 0, stream>>>(hbuf, rowmap, cnt, wt + 4 * WSZ, out, CH0);
}